// Round 7
// baseline (360.443 us; speedup 1.0000x reference)
//
#include <hip/hip_runtime.h>
#include <math.h>

#define NN 4096
#define CC 256

typedef unsigned short u16;
typedef float f32x16 __attribute__((ext_vector_type(16)));
typedef short s16x8 __attribute__((ext_vector_type(8)));

#define ZERO16 {0.f,0.f,0.f,0.f,0.f,0.f,0.f,0.f,0.f,0.f,0.f,0.f,0.f,0.f,0.f,0.f}

#define GLOAD_LDS16(gsrc, ldst) \
    __builtin_amdgcn_global_load_lds((const __attribute__((address_space(1))) unsigned int*)(gsrc), \
                                     (__attribute__((address_space(3))) unsigned int*)(ldst), 16, 0, 0)

__device__ __forceinline__ u16 f2bf(float f){
    unsigned u = __float_as_uint(f);
    return (u16)((u + 0x7fffu + ((u >> 16) & 1u)) >> 16);
}
__device__ __forceinline__ float bf2f(u16 h){
    return __uint_as_float(((unsigned)h) << 16);
}

// ---------------------------------------------------------------- gate + W prep
__global__ __launch_bounds__(256) void gate_kernel(
    const float* __restrict__ g0, const float* __restrict__ Wq,
    const float* __restrict__ Wk, const float* __restrict__ Wv,
    float* __restrict__ gate,
    u16* __restrict__ wqhi, u16* __restrict__ wqlo,
    u16* __restrict__ wkhi, u16* __restrict__ wklo,
    u16* __restrict__ wvbf)
{
    int idx = blockIdx.x * 256 + threadIdx.x;      // 0..16383
    int b  = idx >> 12;
    int hw = idx & 4095;
    int h = hw >> 6, w = hw & 63;
    float ys = h * (31.0f / 63.0f);
    float xs = w * (31.0f / 63.0f);
    int y0 = (int)ys, x0 = (int)xs;
    int y1 = min(y0 + 1, 31), x1 = min(x0 + 1, 31);
    float wy = ys - (float)y0, wx = xs - (float)x0;
    const float* g = g0 + b * 1024;
    float g00 = g[y0 * 32 + x0], g01 = g[y0 * 32 + x1];
    float g10 = g[y1 * 32 + x0], g11 = g[y1 * 32 + x1];
    float top = g00 * (1.0f - wx) + g01 * wx;
    float bot = g10 * (1.0f - wx) + g11 * wx;
    float val = top * (1.0f - wy) + bot * wy;
    gate[idx] = 1.0f + 1.0f / (1.0f + __expf(-val));

    if (idx < 8192) {
        float a = Wq[idx];
        u16 ha = f2bf(a);
        wqhi[idx] = ha; wqlo[idx] = f2bf(a - bf2f(ha));
        float c = Wk[idx];
        u16 hc = f2bf(c);
        wkhi[idx] = hc; wklo[idx] = f2bf(c - bf2f(hc));
    }
#pragma unroll
    for (int j = 0; j < 4; j++)
        wvbf[idx + j * 16384] = f2bf(Wv[idx + j * 16384]);
}

// ---------------------------------------------------------------- qkv -----
// 256 blocks (b, nt of 64 n). x staged once in LDS as bf16 hi/lo [n][c] swizzled.
// 8 waves: 0..3 = q/k (proj, nhalf) hi/lo-split MFMA; 4..7 = v (64 c each).
// q/k written PACKED: row [n][hi0..hi31 | lo0..lo31] (128 B per n).
__global__ __launch_bounds__(512, 4) void qkv_kernel(
    const float* __restrict__ x,
    const u16* __restrict__ wqhi, const u16* __restrict__ wqlo,
    const u16* __restrict__ wkhi, const u16* __restrict__ wklo,
    const u16* __restrict__ wvbf,
    const float* __restrict__ bq, const float* __restrict__ bk,
    const float* __restrict__ bv, const float* __restrict__ gate,
    u16* __restrict__ qpk, u16* __restrict__ kpk,
    u16* __restrict__ vbf)
{
    __shared__ u16 Xh[64 * 256];   // [n][c] swizzled, 32 KB
    __shared__ u16 Xl[64 * 256];   // 32 KB
    int bid = blockIdx.x;
    int b  = (bid >> 1) & 3;
    int nt = (bid >> 3) | ((bid & 1) << 5);
    int n0 = nt * 64;
    int tid = threadIdx.x;

    // ---- stage x -> LDS (hi/lo bf16, [n][c], XOR-swizzled rows)
    {
        const float* xb = x + (size_t)b * CC * NN;
        int cb = tid >> 4;          // 0..31
        int nc = tid & 15;          // 4-n chunk
#pragma unroll
        for (int j = 0; j < 8; j++) {
            int c = cb + 32 * j;
            float4 xv = *(const float4*)(xb + (size_t)c * NN + n0 + nc * 4);
            float xf[4] = {xv.x, xv.y, xv.z, xv.w};
#pragma unroll
            for (int i = 0; i < 4; i++) {
                int n = nc * 4 + i;
                u16 hv = f2bf(xf[i]);
                u16 lv = f2bf(xf[i] - bf2f(hv));
                int u = n * 256 + (c ^ ((n & 31) << 3));
                Xh[u] = hv; Xl[u] = lv;
            }
        }
    }
    __syncthreads();

    int w = tid >> 6, l = tid & 63;
    int l5 = l >> 5, l31 = l & 31;

    if (w < 4) {
        // ---- q,k
        int proj = w & 1, nh = w >> 1;
        const u16* Whi = proj ? wkhi : wqhi;
        const u16* Wlo = proj ? wklo : wqlo;
        const float* bias = proj ? bk : bq;
        u16* dpk = proj ? kpk : qpk;
        int nl = nh * 32 + l31;
        int swz = (nl & 31) << 3;

        f32x16 acc = ZERO16;
        for (int ks = 0; ks < 16; ks++) {
            int c0 = ks * 16 + 8 * l5;
            s16x8 whi = *(const s16x8*)(Whi + l31 * 256 + c0);
            s16x8 wlo = *(const s16x8*)(Wlo + l31 * 256 + c0);
            int u = nl * 256 + (c0 ^ swz);
            s16x8 xh = *(const s16x8*)(Xh + u);
            s16x8 xl = *(const s16x8*)(Xl + u);
            acc = __builtin_amdgcn_mfma_f32_32x32x16_bf16(whi, xh, acc, 0, 0, 0);
            acc = __builtin_amdgcn_mfma_f32_32x32x16_bf16(whi, xl, acc, 0, 0, 0);
            acc = __builtin_amdgcn_mfma_f32_32x32x16_bf16(wlo, xh, acc, 0, 0, 0);
        }
        int n = n0 + nl;
        float g = gate[b * NN + n];
        size_t rowo = ((size_t)b * NN + n) * 64;
#pragma unroll
        for (int t = 0; t < 4; t++) {
            int ob = 8 * t + 4 * l5;
            unsigned h01 = 0, h23 = 0, l01 = 0, l23 = 0;
#pragma unroll
            for (int j = 0; j < 4; j++) {
                float v = (acc[4 * t + j] + bias[ob + j]) * g;
                u16 h = f2bf(v);
                u16 lo = f2bf(v - bf2f(h));
                if (j < 2) { h01 |= ((unsigned)h) << (16 * j); l01 |= ((unsigned)lo) << (16 * j); }
                else       { h23 |= ((unsigned)h) << (16 * (j - 2)); l23 |= ((unsigned)lo) << (16 * (j - 2)); }
            }
            *(unsigned*)(dpk + rowo + ob)          = h01;
            *(unsigned*)(dpk + rowo + ob + 2)      = h23;
            *(unsigned*)(dpk + rowo + 32 + ob)     = l01;
            *(unsigned*)(dpk + rowo + 32 + ob + 2) = l23;
        }
    } else {
        // ---- v: wave covers 64 c x 64 n
        int vw = w - 4;
        int cB = vw * 64;
        int swz = (l31 & 31) << 3;
        f32x16 acc[2][2] = {{ZERO16, ZERO16}, {ZERO16, ZERO16}};
        for (int ks = 0; ks < 16; ks++) {
            int c0 = ks * 16 + 8 * l5;
            int u0 = l31 * 256 + (c0 ^ swz);
            s16x8 xh0 = *(const s16x8*)(Xh + u0);
            s16x8 xh1 = *(const s16x8*)(Xh + u0 + 32 * 256);
#pragma unroll
            for (int ct = 0; ct < 2; ct++) {
                s16x8 wv = *(const s16x8*)(wvbf + (size_t)(cB + ct * 32 + l31) * 256 + c0);
                acc[ct][0] = __builtin_amdgcn_mfma_f32_32x32x16_bf16(wv, xh0, acc[ct][0], 0, 0, 0);
                acc[ct][1] = __builtin_amdgcn_mfma_f32_32x32x16_bf16(wv, xh1, acc[ct][1], 0, 0, 0);
            }
        }
#pragma unroll
        for (int nh2 = 0; nh2 < 2; nh2++) {
            int n = n0 + nh2 * 32 + l31;
            float g = gate[b * NN + n];
#pragma unroll
            for (int ct = 0; ct < 2; ct++) {
#pragma unroll
                for (int r = 0; r < 16; r++) {
                    int c = cB + ct * 32 + (r & 3) + 8 * (r >> 2) + 4 * l5;
                    vbf[((size_t)b * CC + c) * NN + n] = f2bf((acc[ct][nh2][r] + bv[c]) * g);
                }
            }
        }
    }
}

// ---------------------------------------------------------------- stats ---
// 256 blocks x 8 waves (strip, ns). K packed direct from global, no in-loop barriers.
__global__ __launch_bounds__(512, 4) void stats_kernel(
    const u16* __restrict__ qpk, const u16* __restrict__ kpk,
    float* __restrict__ lse)
{
    __shared__ float Sm[8][2][16], Ss[8][2][16];
    int bid = blockIdx.x;
    int b  = (bid >> 1) & 3;
    int mt = (bid >> 3) | ((bid & 1) << 5);
    int tid = threadIdx.x;
    int w = tid >> 6, l = tid & 63;
    int l5 = l >> 5, l31 = l & 31;
    int strip = w & 1, ns = w >> 1;
    int mS = mt * 64 + strip * 32;

    size_t qo = ((size_t)b * NN + mS + l31) * 64 + 8 * l5;
    s16x8 qh0 = *(const s16x8*)(qpk + qo),      ql0 = *(const s16x8*)(qpk + qo + 32);
    s16x8 qh1 = *(const s16x8*)(qpk + qo + 16), ql1 = *(const s16x8*)(qpk + qo + 48);

    float rmax[16], rsum[16];
#pragma unroll
    for (int r = 0; r < 16; r++) { rmax[r] = -1e30f; rsum[r] = 0.f; }

    for (int it = 0; it < 32; it++) {
        size_t ko = ((size_t)b * NN + it * 128 + ns * 32 + l31) * 64 + 8 * l5;
        s16x8 kh0 = *(const s16x8*)(kpk + ko),      kl0 = *(const s16x8*)(kpk + ko + 32);
        s16x8 kh1 = *(const s16x8*)(kpk + ko + 16), kl1 = *(const s16x8*)(kpk + ko + 48);
        f32x16 a = ZERO16;
        a = __builtin_amdgcn_mfma_f32_32x32x16_bf16(ql0, kh0, a, 0, 0, 0);
        a = __builtin_amdgcn_mfma_f32_32x32x16_bf16(qh0, kl0, a, 0, 0, 0);
        a = __builtin_amdgcn_mfma_f32_32x32x16_bf16(qh0, kh0, a, 0, 0, 0);
        a = __builtin_amdgcn_mfma_f32_32x32x16_bf16(ql1, kh1, a, 0, 0, 0);
        a = __builtin_amdgcn_mfma_f32_32x32x16_bf16(qh1, kl1, a, 0, 0, 0);
        a = __builtin_amdgcn_mfma_f32_32x32x16_bf16(qh1, kh1, a, 0, 0, 0);
#pragma unroll
        for (int r = 0; r < 16; r++) {
            float nm = fmaxf(rmax[r], a[r]);
            rsum[r] = rsum[r] * __expf(rmax[r] - nm) + __expf(a[r] - nm);
            rmax[r] = nm;
        }
    }

#pragma unroll
    for (int r = 0; r < 16; r++) {
#pragma unroll
        for (int off = 16; off >= 1; off >>= 1) {
            float om = __shfl_xor(rmax[r], off);
            float os = __shfl_xor(rsum[r], off);
            float nm = fmaxf(rmax[r], om);
            rsum[r] = rsum[r] * __expf(rmax[r] - nm) + os * __expf(om - nm);
            rmax[r] = nm;
        }
    }
    if (l31 == 0) {
#pragma unroll
        for (int r = 0; r < 16; r++) { Sm[w][l5][r] = rmax[r]; Ss[w][l5][r] = rsum[r]; }
    }
    __syncthreads();
    if (w < 2 && l31 == 0) {
#pragma unroll
        for (int r = 0; r < 16; r++) {
            float M = -1e30f;
#pragma unroll
            for (int j = 0; j < 4; j++) M = fmaxf(M, Sm[w + 2 * j][l5][r]);
            float S = 0.f;
#pragma unroll
            for (int j = 0; j < 4; j++)
                S += Ss[w + 2 * j][l5][r] * __expf(Sm[w + 2 * j][l5][r] - M);
            int m = mt * 64 + w * 32 + (r & 3) + 8 * (r >> 2) + 4 * l5;
            lse[b * NN + m] = M + __logf(S);
        }
    }
}

// ---------------------------------------------------------------- out -----
// 512 blocks: sub=bid&7 -> b=sub>>1, ch=sub&1 (c-half 128); mt=bid>>3.
// Block: 64 m x 128 c, n-tile 128, LDS 48 KB -> 3 blocks/CU.
// 8 waves = (strip=w&1, cq=w>>1): energy S-tile (strip, n-sub cq); PV owns
// 32 m x 32 c, sums all 128 n. V staged via global_load_lds (inv-swizzled src).
__global__ __launch_bounds__(512, 6) void out_kernel(
    const u16* __restrict__ qpk, const u16* __restrict__ kpk,
    const u16* __restrict__ vbf, const float* __restrict__ lse,
    const float* __restrict__ x, const float* __restrict__ gamma,
    float* __restrict__ out)
{
    __shared__ u16 Vl[128 * 128];   // [c_local][n] swizzled, 32 KB
    __shared__ u16 Pl[64 * 128];    // [m][n] swizzled, 16 KB
    int bid = blockIdx.x;
    int sub = bid & 7;
    int b  = sub >> 1;
    int ch = sub & 1;
    int mt = bid >> 3;
    int tid = threadIdx.x;
    int w = tid >> 6, l = tid & 63;
    int l5 = l >> 5, l31 = l & 31;
    int strip = w & 1, cq = w >> 1;
    int mS = mt * 64 + strip * 32;

    size_t qo = ((size_t)b * NN + mS + l31) * 64 + 8 * l5;
    s16x8 qh0 = *(const s16x8*)(qpk + qo),      ql0 = *(const s16x8*)(qpk + qo + 32);
    s16x8 qh1 = *(const s16x8*)(qpk + qo + 16), ql1 = *(const s16x8*)(qpk + qo + 48);

    float lr[16];
#pragma unroll
    for (int r = 0; r < 16; r++)
        lr[r] = lse[b * NN + mS + (r & 3) + 8 * (r >> 2) + 4 * l5];

    f32x16 acc = ZERO16;
    const u16* vb = vbf + ((size_t)b * CC + ch * 128) * NN;

    for (int it = 0; it < 32; it++) {
        int n0 = it * 128;
        // ---- stage V: 32 KB, 4 x gload_lds16 per thread.
        // LDS dest base MUST be wave-uniform (HW adds lane*16): include w*64.
#pragma unroll
        for (int j = 0; j < 4; j++) {
            int s = j * 512 + w * 64 + l;
            int c = s >> 4, chk = s & 15;
            const u16* src = vb + (size_t)c * NN + n0 + ((chk * 8) ^ ((c & 15) << 3));
            GLOAD_LDS16(src, Vl + (size_t)(j * 512 + w * 64) * 8);
        }
        // ---- energy: S-tile (strip, n-sub cq), K packed direct from global
        {
            size_t ko = ((size_t)b * NN + n0 + cq * 32 + l31) * 64 + 8 * l5;
            s16x8 kh0 = *(const s16x8*)(kpk + ko),      kl0 = *(const s16x8*)(kpk + ko + 32);
            s16x8 kh1 = *(const s16x8*)(kpk + ko + 16), kl1 = *(const s16x8*)(kpk + ko + 48);
            f32x16 a = ZERO16;
            a = __builtin_amdgcn_mfma_f32_32x32x16_bf16(ql0, kh0, a, 0, 0, 0);
            a = __builtin_amdgcn_mfma_f32_32x32x16_bf16(qh0, kl0, a, 0, 0, 0);
            a = __builtin_amdgcn_mfma_f32_32x32x16_bf16(qh0, kh0, a, 0, 0, 0);
            a = __builtin_amdgcn_mfma_f32_32x32x16_bf16(ql1, kh1, a, 0, 0, 0);
            a = __builtin_amdgcn_mfma_f32_32x32x16_bf16(qh1, kl1, a, 0, 0, 0);
            a = __builtin_amdgcn_mfma_f32_32x32x16_bf16(qh1, kh1, a, 0, 0, 0);
#pragma unroll
            for (int r = 0; r < 16; r++) {
                float p = __expf(a[r] - lr[r]);
                int m = strip * 32 + (r & 3) + 8 * (r >> 2) + 4 * l5;
                int nc = cq * 32 + l31;
                Pl[m * 128 + (nc ^ ((m & 15) << 3))] = f2bf(p);
            }
        }
        __syncthreads();
        // ---- PV: wave owns (m strip*32..+32) x (c_local cq*32..+32), all 128 n
#pragma unroll
        for (int ks = 0; ks < 8; ks++) {
            int col = ks * 16 + 8 * l5;
            int mr = strip * 32 + l31;
            int cr = cq * 32 + l31;
            s16x8 pa = *(const s16x8*)(Pl + mr * 128 + (col ^ ((mr & 15) << 3)));
            s16x8 vv = *(const s16x8*)(Vl + cr * 128 + (col ^ ((cr & 15) << 3)));
            acc = __builtin_amdgcn_mfma_f32_32x32x16_bf16(pa, vv, acc, 0, 0, 0);
        }
        __syncthreads();
    }

    float gm = gamma[0];
    int c = ch * 128 + cq * 32 + l31;
#pragma unroll
    for (int t = 0; t < 4; t++) {
        size_t o = ((size_t)b * CC + c) * NN + mS + 8 * t + 4 * l5;
        float4 x4 = *(const float4*)(x + o);
        float4 r4;
        r4.x = fmaf(gm, acc[4 * t + 0], x4.x);
        r4.y = fmaf(gm, acc[4 * t + 1], x4.y);
        r4.z = fmaf(gm, acc[4 * t + 2], x4.z);
        r4.w = fmaf(gm, acc[4 * t + 3], x4.w);
        *(float4*)(out + o) = r4;
    }
}

// ---------------------------------------------------------------- launch --
extern "C" void kernel_launch(void* const* d_in, const int* in_sizes, int n_in,
                              void* d_out, int out_size, void* d_ws, size_t ws_size,
                              hipStream_t stream)
{
    const float* x     = (const float*)d_in[0];
    const float* g0    = (const float*)d_in[1];
    const float* Wq    = (const float*)d_in[2];
    const float* bq    = (const float*)d_in[3];
    const float* Wk    = (const float*)d_in[4];
    const float* bk    = (const float*)d_in[5];
    const float* Wv    = (const float*)d_in[6];
    const float* bv    = (const float*)d_in[7];
    const float* gamma = (const float*)d_in[8];
    float* out = (float*)d_out;

    char* p = (char*)d_ws;
    u16* qpk = (u16*)p; p += (size_t)4 * NN * 64 * 2;   // 2 MB packed [n][hi|lo]
    u16* kpk = (u16*)p; p += (size_t)4 * NN * 64 * 2;   // 2 MB
    u16* vbf = (u16*)p; p += (size_t)4 * CC * NN * 2;   // 8 MB
    float* gate = (float*)p; p += (size_t)4 * NN * 4;
    float* lse  = (float*)p; p += (size_t)4 * NN * 4;
    u16* wqhi = (u16*)p; p += 8192 * 2;
    u16* wqlo = (u16*)p; p += 8192 * 2;
    u16* wkhi = (u16*)p; p += 8192 * 2;
    u16* wklo = (u16*)p; p += 8192 * 2;
    u16* wvbf = (u16*)p; p += 65536 * 2;

    hipLaunchKernelGGL(gate_kernel, dim3(64), dim3(256), 0, stream,
                       g0, Wq, Wk, Wv, gate, wqhi, wqlo, wkhi, wklo, wvbf);
    hipLaunchKernelGGL(qkv_kernel, dim3(256), dim3(512), 0, stream,
                       x, wqhi, wqlo, wkhi, wklo, wvbf, bq, bk, bv, gate,
                       qpk, kpk, vbf);
    hipLaunchKernelGGL(stats_kernel, dim3(256), dim3(512), 0, stream,
                       qpk, kpk, lse);
    hipLaunchKernelGGL(out_kernel, dim3(512), dim3(512), 0, stream,
                       qpk, kpk, vbf, lse, x, gamma, out);
}

// Round 8
// 161.592 us; speedup vs baseline: 2.2306x; 2.2306x over previous
//
#include <hip/hip_runtime.h>
#include <math.h>

#define NN 4096
#define CC 256

typedef unsigned short u16;
typedef float f32x16 __attribute__((ext_vector_type(16)));
typedef short s16x8 __attribute__((ext_vector_type(8)));

#define ZERO16 {0.f,0.f,0.f,0.f,0.f,0.f,0.f,0.f,0.f,0.f,0.f,0.f,0.f,0.f,0.f,0.f}

#define GLOAD_LDS16(gsrc, ldst) \
    __builtin_amdgcn_global_load_lds((const __attribute__((address_space(1))) unsigned int*)(gsrc), \
                                     (__attribute__((address_space(3))) unsigned int*)(ldst), 16, 0, 0)

__device__ __forceinline__ u16 f2bf(float f){
    unsigned u = __float_as_uint(f);
    return (u16)((u + 0x7fffu + ((u >> 16) & 1u)) >> 16);
}
__device__ __forceinline__ float bf2f(u16 h){
    return __uint_as_float(((unsigned)h) << 16);
}

// ---------------------------------------------------------------- gate + W prep
__global__ __launch_bounds__(256) void gate_kernel(
    const float* __restrict__ g0, const float* __restrict__ Wq,
    const float* __restrict__ Wk, const float* __restrict__ Wv,
    float* __restrict__ gate,
    u16* __restrict__ wqhi, u16* __restrict__ wqlo,
    u16* __restrict__ wkhi, u16* __restrict__ wklo,
    u16* __restrict__ wvbf)
{
    int idx = blockIdx.x * 256 + threadIdx.x;      // 0..16383
    int b  = idx >> 12;
    int hw = idx & 4095;
    int h = hw >> 6, w = hw & 63;
    float ys = h * (31.0f / 63.0f);
    float xs = w * (31.0f / 63.0f);
    int y0 = (int)ys, x0 = (int)xs;
    int y1 = min(y0 + 1, 31), x1 = min(x0 + 1, 31);
    float wy = ys - (float)y0, wx = xs - (float)x0;
    const float* g = g0 + b * 1024;
    float g00 = g[y0 * 32 + x0], g01 = g[y0 * 32 + x1];
    float g10 = g[y1 * 32 + x0], g11 = g[y1 * 32 + x1];
    float top = g00 * (1.0f - wx) + g01 * wx;
    float bot = g10 * (1.0f - wx) + g11 * wx;
    float val = top * (1.0f - wy) + bot * wy;
    gate[idx] = 1.0f + 1.0f / (1.0f + __expf(-val));

    if (idx < 8192) {
        float a = Wq[idx];
        u16 ha = f2bf(a);
        wqhi[idx] = ha; wqlo[idx] = f2bf(a - bf2f(ha));
        float c = Wk[idx];
        u16 hc = f2bf(c);
        wkhi[idx] = hc; wklo[idx] = f2bf(c - bf2f(hc));
    }
#pragma unroll
    for (int j = 0; j < 4; j++)
        wvbf[idx + j * 16384] = f2bf(Wv[idx + j * 16384]);
}

// ---------------------------------------------------------------- qkv -----
// 256 blocks (b, nt of 64 n). x staged once in LDS as bf16 hi/lo [n][c] swizzled.
// 8 waves: 0..3 = q/k (proj, nhalf) hi/lo-split MFMA; 4..7 = v (64 c each).
// q/k written PACKED: row [n][hi0..hi31 | lo0..lo31] (128 B per n).
__global__ __launch_bounds__(512, 4) void qkv_kernel(
    const float* __restrict__ x,
    const u16* __restrict__ wqhi, const u16* __restrict__ wqlo,
    const u16* __restrict__ wkhi, const u16* __restrict__ wklo,
    const u16* __restrict__ wvbf,
    const float* __restrict__ bq, const float* __restrict__ bk,
    const float* __restrict__ bv, const float* __restrict__ gate,
    u16* __restrict__ qpk, u16* __restrict__ kpk,
    u16* __restrict__ vbf)
{
    __shared__ u16 Xh[64 * 256];   // [n][c] swizzled, 32 KB
    __shared__ u16 Xl[64 * 256];   // 32 KB
    int bid = blockIdx.x;
    int b  = (bid >> 1) & 3;
    int nt = (bid >> 3) | ((bid & 1) << 5);
    int n0 = nt * 64;
    int tid = threadIdx.x;

    // ---- stage x -> LDS (hi/lo bf16, [n][c], XOR-swizzled rows)
    {
        const float* xb = x + (size_t)b * CC * NN;
        int cb = tid >> 4;          // 0..31
        int nc = tid & 15;          // 4-n chunk
#pragma unroll
        for (int j = 0; j < 8; j++) {
            int c = cb + 32 * j;
            float4 xv = *(const float4*)(xb + (size_t)c * NN + n0 + nc * 4);
            float xf[4] = {xv.x, xv.y, xv.z, xv.w};
#pragma unroll
            for (int i = 0; i < 4; i++) {
                int n = nc * 4 + i;
                u16 hv = f2bf(xf[i]);
                u16 lv = f2bf(xf[i] - bf2f(hv));
                int u = n * 256 + (c ^ ((n & 31) << 3));
                Xh[u] = hv; Xl[u] = lv;
            }
        }
    }
    __syncthreads();

    int w = tid >> 6, l = tid & 63;
    int l5 = l >> 5, l31 = l & 31;

    if (w < 4) {
        // ---- q,k
        int proj = w & 1, nh = w >> 1;
        const u16* Whi = proj ? wkhi : wqhi;
        const u16* Wlo = proj ? wklo : wqlo;
        const float* bias = proj ? bk : bq;
        u16* dpk = proj ? kpk : qpk;
        int nl = nh * 32 + l31;
        int swz = (nl & 31) << 3;

        f32x16 acc = ZERO16;
        for (int ks = 0; ks < 16; ks++) {
            int c0 = ks * 16 + 8 * l5;
            s16x8 whi = *(const s16x8*)(Whi + l31 * 256 + c0);
            s16x8 wlo = *(const s16x8*)(Wlo + l31 * 256 + c0);
            int u = nl * 256 + (c0 ^ swz);
            s16x8 xh = *(const s16x8*)(Xh + u);
            s16x8 xl = *(const s16x8*)(Xl + u);
            acc = __builtin_amdgcn_mfma_f32_32x32x16_bf16(whi, xh, acc, 0, 0, 0);
            acc = __builtin_amdgcn_mfma_f32_32x32x16_bf16(whi, xl, acc, 0, 0, 0);
            acc = __builtin_amdgcn_mfma_f32_32x32x16_bf16(wlo, xh, acc, 0, 0, 0);
        }
        int n = n0 + nl;
        float g = gate[b * NN + n];
        size_t rowo = ((size_t)b * NN + n) * 64;
#pragma unroll
        for (int t = 0; t < 4; t++) {
            int ob = 8 * t + 4 * l5;
            unsigned h01 = 0, h23 = 0, l01 = 0, l23 = 0;
#pragma unroll
            for (int j = 0; j < 4; j++) {
                float v = (acc[4 * t + j] + bias[ob + j]) * g;
                u16 h = f2bf(v);
                u16 lo = f2bf(v - bf2f(h));
                if (j < 2) { h01 |= ((unsigned)h) << (16 * j); l01 |= ((unsigned)lo) << (16 * j); }
                else       { h23 |= ((unsigned)h) << (16 * (j - 2)); l23 |= ((unsigned)lo) << (16 * (j - 2)); }
            }
            *(unsigned*)(dpk + rowo + ob)          = h01;
            *(unsigned*)(dpk + rowo + ob + 2)      = h23;
            *(unsigned*)(dpk + rowo + 32 + ob)     = l01;
            *(unsigned*)(dpk + rowo + 32 + ob + 2) = l23;
        }
    } else {
        // ---- v: wave covers 64 c x 64 n
        int vw = w - 4;
        int cB = vw * 64;
        int swz = (l31 & 31) << 3;
        f32x16 acc[2][2] = {{ZERO16, ZERO16}, {ZERO16, ZERO16}};
        for (int ks = 0; ks < 16; ks++) {
            int c0 = ks * 16 + 8 * l5;
            int u0 = l31 * 256 + (c0 ^ swz);
            s16x8 xh0 = *(const s16x8*)(Xh + u0);
            s16x8 xh1 = *(const s16x8*)(Xh + u0 + 32 * 256);
#pragma unroll
            for (int ct = 0; ct < 2; ct++) {
                s16x8 wv = *(const s16x8*)(wvbf + (size_t)(cB + ct * 32 + l31) * 256 + c0);
                acc[ct][0] = __builtin_amdgcn_mfma_f32_32x32x16_bf16(wv, xh0, acc[ct][0], 0, 0, 0);
                acc[ct][1] = __builtin_amdgcn_mfma_f32_32x32x16_bf16(wv, xh1, acc[ct][1], 0, 0, 0);
            }
        }
#pragma unroll
        for (int nh2 = 0; nh2 < 2; nh2++) {
            int n = n0 + nh2 * 32 + l31;
            float g = gate[b * NN + n];
#pragma unroll
            for (int ct = 0; ct < 2; ct++) {
#pragma unroll
                for (int r = 0; r < 16; r++) {
                    int c = cB + ct * 32 + (r & 3) + 8 * (r >> 2) + 4 * l5;
                    vbf[((size_t)b * CC + c) * NN + n] = f2bf((acc[ct][nh2][r] + bv[c]) * g);
                }
            }
        }
    }
}

// ---------------------------------------------------------------- stats ---
// 256 blocks x 8 waves (strip, ns). K packed direct from global, no in-loop barriers.
__global__ __launch_bounds__(512, 4) void stats_kernel(
    const u16* __restrict__ qpk, const u16* __restrict__ kpk,
    float* __restrict__ lse)
{
    __shared__ float Sm[8][2][16], Ss[8][2][16];
    int bid = blockIdx.x;
    int b  = (bid >> 1) & 3;
    int mt = (bid >> 3) | ((bid & 1) << 5);
    int tid = threadIdx.x;
    int w = tid >> 6, l = tid & 63;
    int l5 = l >> 5, l31 = l & 31;
    int strip = w & 1, ns = w >> 1;
    int mS = mt * 64 + strip * 32;

    size_t qo = ((size_t)b * NN + mS + l31) * 64 + 8 * l5;
    s16x8 qh0 = *(const s16x8*)(qpk + qo),      ql0 = *(const s16x8*)(qpk + qo + 32);
    s16x8 qh1 = *(const s16x8*)(qpk + qo + 16), ql1 = *(const s16x8*)(qpk + qo + 48);

    float rmax[16], rsum[16];
#pragma unroll
    for (int r = 0; r < 16; r++) { rmax[r] = -1e30f; rsum[r] = 0.f; }

    for (int it = 0; it < 32; it++) {
        size_t ko = ((size_t)b * NN + it * 128 + ns * 32 + l31) * 64 + 8 * l5;
        s16x8 kh0 = *(const s16x8*)(kpk + ko),      kl0 = *(const s16x8*)(kpk + ko + 32);
        s16x8 kh1 = *(const s16x8*)(kpk + ko + 16), kl1 = *(const s16x8*)(kpk + ko + 48);
        f32x16 a = ZERO16;
        a = __builtin_amdgcn_mfma_f32_32x32x16_bf16(ql0, kh0, a, 0, 0, 0);
        a = __builtin_amdgcn_mfma_f32_32x32x16_bf16(qh0, kl0, a, 0, 0, 0);
        a = __builtin_amdgcn_mfma_f32_32x32x16_bf16(qh0, kh0, a, 0, 0, 0);
        a = __builtin_amdgcn_mfma_f32_32x32x16_bf16(ql1, kh1, a, 0, 0, 0);
        a = __builtin_amdgcn_mfma_f32_32x32x16_bf16(qh1, kl1, a, 0, 0, 0);
        a = __builtin_amdgcn_mfma_f32_32x32x16_bf16(qh1, kh1, a, 0, 0, 0);
#pragma unroll
        for (int r = 0; r < 16; r++) {
            float nm = fmaxf(rmax[r], a[r]);
            rsum[r] = rsum[r] * __expf(rmax[r] - nm) + __expf(a[r] - nm);
            rmax[r] = nm;
        }
    }

#pragma unroll
    for (int r = 0; r < 16; r++) {
#pragma unroll
        for (int off = 16; off >= 1; off >>= 1) {
            float om = __shfl_xor(rmax[r], off);
            float os = __shfl_xor(rsum[r], off);
            float nm = fmaxf(rmax[r], om);
            rsum[r] = rsum[r] * __expf(rmax[r] - nm) + os * __expf(om - nm);
            rmax[r] = nm;
        }
    }
    if (l31 == 0) {
#pragma unroll
        for (int r = 0; r < 16; r++) { Sm[w][l5][r] = rmax[r]; Ss[w][l5][r] = rsum[r]; }
    }
    __syncthreads();
    if (w < 2 && l31 == 0) {
#pragma unroll
        for (int r = 0; r < 16; r++) {
            float M = -1e30f;
#pragma unroll
            for (int j = 0; j < 4; j++) M = fmaxf(M, Sm[w + 2 * j][l5][r]);
            float S = 0.f;
#pragma unroll
            for (int j = 0; j < 4; j++)
                S += Ss[w + 2 * j][l5][r] * __expf(Sm[w + 2 * j][l5][r] - M);
            int m = mt * 64 + w * 32 + (r & 3) + 8 * (r >> 2) + 4 * l5;
            lse[b * NN + m] = M + __logf(S);
        }
    }
}

// ---------------------------------------------------------------- out -----
// 512 blocks: sub=bid&7 -> b=sub>>1, ch=sub&1 (c-half 128); mt=bid>>3.
// Block: 64 m x 128 c, n-tile 128, LDS 48 KB. __launch_bounds__(512,2):
// natural ~84 VGPR -> 6 waves/EU -> 3 blocks/CU (LDS 144<=160 KB).
// 8 waves = (strip=w&1, cq=w>>1): energy S-tile (strip, n-sub cq); PV owns
// 32 m x 32 c, sums all 128 n. V staged via global_load_lds (inv-swizzled src).
__global__ __launch_bounds__(512, 2) void out_kernel(
    const u16* __restrict__ qpk, const u16* __restrict__ kpk,
    const u16* __restrict__ vbf, const float* __restrict__ lse,
    const float* __restrict__ x, const float* __restrict__ gamma,
    float* __restrict__ out)
{
    __shared__ u16 Vl[128 * 128];   // [c_local][n] swizzled, 32 KB
    __shared__ u16 Pl[64 * 128];    // [m][n] swizzled, 16 KB
    int bid = blockIdx.x;
    int sub = bid & 7;
    int b  = sub >> 1;
    int ch = sub & 1;
    int mt = bid >> 3;
    int tid = threadIdx.x;
    int w = tid >> 6, l = tid & 63;
    int l5 = l >> 5, l31 = l & 31;
    int strip = w & 1, cq = w >> 1;
    int mS = mt * 64 + strip * 32;

    size_t qo = ((size_t)b * NN + mS + l31) * 64 + 8 * l5;
    s16x8 qh0 = *(const s16x8*)(qpk + qo),      ql0 = *(const s16x8*)(qpk + qo + 32);
    s16x8 qh1 = *(const s16x8*)(qpk + qo + 16), ql1 = *(const s16x8*)(qpk + qo + 48);

    float lr[16];
#pragma unroll
    for (int r = 0; r < 16; r++)
        lr[r] = lse[b * NN + mS + (r & 3) + 8 * (r >> 2) + 4 * l5];

    f32x16 acc = ZERO16;
    const u16* vb = vbf + ((size_t)b * CC + ch * 128) * NN;

    for (int it = 0; it < 32; it++) {
        int n0 = it * 128;
        // ---- stage V: 32 KB, 4 x gload_lds16 per thread.
        // LDS dest base wave-uniform (HW adds lane*16): include w*64.
#pragma unroll
        for (int j = 0; j < 4; j++) {
            int s = j * 512 + w * 64 + l;
            int c = s >> 4, chk = s & 15;
            const u16* src = vb + (size_t)c * NN + n0 + ((chk * 8) ^ ((c & 15) << 3));
            GLOAD_LDS16(src, Vl + (size_t)(j * 512 + w * 64) * 8);
        }
        // ---- energy: S-tile (strip, n-sub cq), K packed direct from global
        {
            size_t ko = ((size_t)b * NN + n0 + cq * 32 + l31) * 64 + 8 * l5;
            s16x8 kh0 = *(const s16x8*)(kpk + ko),      kl0 = *(const s16x8*)(kpk + ko + 32);
            s16x8 kh1 = *(const s16x8*)(kpk + ko + 16), kl1 = *(const s16x8*)(kpk + ko + 48);
            f32x16 a = ZERO16;
            a = __builtin_amdgcn_mfma_f32_32x32x16_bf16(ql0, kh0, a, 0, 0, 0);
            a = __builtin_amdgcn_mfma_f32_32x32x16_bf16(qh0, kl0, a, 0, 0, 0);
            a = __builtin_amdgcn_mfma_f32_32x32x16_bf16(qh0, kh0, a, 0, 0, 0);
            a = __builtin_amdgcn_mfma_f32_32x32x16_bf16(ql1, kh1, a, 0, 0, 0);
            a = __builtin_amdgcn_mfma_f32_32x32x16_bf16(qh1, kl1, a, 0, 0, 0);
            a = __builtin_amdgcn_mfma_f32_32x32x16_bf16(qh1, kh1, a, 0, 0, 0);
#pragma unroll
            for (int r = 0; r < 16; r++) {
                float p = __expf(a[r] - lr[r]);
                int m = strip * 32 + (r & 3) + 8 * (r >> 2) + 4 * l5;
                int nc = cq * 32 + l31;
                Pl[m * 128 + (nc ^ ((m & 15) << 3))] = f2bf(p);
            }
        }
        __syncthreads();
        // ---- PV: wave owns (m strip*32..+32) x (c_local cq*32..+32), all 128 n
#pragma unroll
        for (int ks = 0; ks < 8; ks++) {
            int col = ks * 16 + 8 * l5;
            int mr = strip * 32 + l31;
            int cr = cq * 32 + l31;
            s16x8 pa = *(const s16x8*)(Pl + mr * 128 + (col ^ ((mr & 15) << 3)));
            s16x8 vv = *(const s16x8*)(Vl + cr * 128 + (col ^ ((cr & 15) << 3)));
            acc = __builtin_amdgcn_mfma_f32_32x32x16_bf16(pa, vv, acc, 0, 0, 0);
        }
        __syncthreads();
    }

    float gm = gamma[0];
    int c = ch * 128 + cq * 32 + l31;
#pragma unroll
    for (int t = 0; t < 4; t++) {
        size_t o = ((size_t)b * CC + c) * NN + mS + 8 * t + 4 * l5;
        float4 x4 = *(const float4*)(x + o);
        float4 r4;
        r4.x = fmaf(gm, acc[4 * t + 0], x4.x);
        r4.y = fmaf(gm, acc[4 * t + 1], x4.y);
        r4.z = fmaf(gm, acc[4 * t + 2], x4.z);
        r4.w = fmaf(gm, acc[4 * t + 3], x4.w);
        *(float4*)(out + o) = r4;
    }
}

// ---------------------------------------------------------------- launch --
extern "C" void kernel_launch(void* const* d_in, const int* in_sizes, int n_in,
                              void* d_out, int out_size, void* d_ws, size_t ws_size,
                              hipStream_t stream)
{
    const float* x     = (const float*)d_in[0];
    const float* g0    = (const float*)d_in[1];
    const float* Wq    = (const float*)d_in[2];
    const float* bq    = (const float*)d_in[3];
    const float* Wk    = (const float*)d_in[4];
    const float* bk    = (const float*)d_in[5];
    const float* Wv    = (const float*)d_in[6];
    const float* bv    = (const float*)d_in[7];
    const float* gamma = (const float*)d_in[8];
    float* out = (float*)d_out;

    char* p = (char*)d_ws;
    u16* qpk = (u16*)p; p += (size_t)4 * NN * 64 * 2;   // 2 MB packed [n][hi|lo]
    u16* kpk = (u16*)p; p += (size_t)4 * NN * 64 * 2;   // 2 MB
    u16* vbf = (u16*)p; p += (size_t)4 * CC * NN * 2;   // 8 MB
    float* gate = (float*)p; p += (size_t)4 * NN * 4;
    float* lse  = (float*)p; p += (size_t)4 * NN * 4;
    u16* wqhi = (u16*)p; p += 8192 * 2;
    u16* wqlo = (u16*)p; p += 8192 * 2;
    u16* wkhi = (u16*)p; p += 8192 * 2;
    u16* wklo = (u16*)p; p += 8192 * 2;
    u16* wvbf = (u16*)p; p += 65536 * 2;

    hipLaunchKernelGGL(gate_kernel, dim3(64), dim3(256), 0, stream,
                       g0, Wq, Wk, Wv, gate, wqhi, wqlo, wkhi, wklo, wvbf);
    hipLaunchKernelGGL(qkv_kernel, dim3(256), dim3(512), 0, stream,
                       x, wqhi, wqlo, wkhi, wklo, wvbf, bq, bk, bv, gate,
                       qpk, kpk, vbf);
    hipLaunchKernelGGL(stats_kernel, dim3(256), dim3(512), 0, stream,
                       qpk, kpk, lse);
    hipLaunchKernelGGL(out_kernel, dim3(512), dim3(512), 0, stream,
                       qpk, kpk, vbf, lse, x, gamma, out);
}